// Round 11
// baseline (577.516 us; speedup 1.0000x reference)
//
#include <hip/hip_runtime.h>
#include <hip/hip_bf16.h>

#define TOK 4096
#define HD 1024
#define ID 512
#define NE 64
#define TK 8
#define CAP 1024
#define NROUTE 32768   // TOK*TK
#define NCHUNK 128     // NROUTE/256

typedef __attribute__((ext_vector_type(4))) float f32x4;
typedef __attribute__((ext_vector_type(16))) float f32x16;
typedef __attribute__((ext_vector_type(8))) short s16x8;
typedef __attribute__((ext_vector_type(2))) __bf16 bf16x2;

__device__ __forceinline__ ushort f2bf(float f){
  uint u = __builtin_bit_cast(uint, f);
  u += 0x7fffu + ((u >> 16) & 1u);
  return (ushort)(u >> 16);
}
__device__ __forceinline__ float bf2f(ushort b){
  uint u = ((uint)b) << 16;
  return __builtin_bit_cast(float, u);
}
__device__ __forceinline__ uint2 f4_to_bf4(float4 v){
  bf16x2 p0; p0[0] = (__bf16)v.x; p0[1] = (__bf16)v.y;
  bf16x2 p1; p1[0] = (__bf16)v.z; p1[1] = (__bf16)v.w;
  uint2 r; r.x = __builtin_bit_cast(uint, p0); r.y = __builtin_bit_cast(uint, p1);
  return r;
}
__device__ __forceinline__ short bfs(float f){
  __bf16 h = (__bf16)f;
  return __builtin_bit_cast(short, h);
}
__device__ __forceinline__ s16x8 pack8(f32x4 a, f32x4 b){
  s16x8 r;
  r[0]=bfs(a[0]); r[1]=bfs(a[1]); r[2]=bfs(a[2]); r[3]=bfs(a[3]);
  r[4]=bfs(b[0]); r[5]=bfs(b[1]); r[6]=bfs(b[2]); r[7]=bfs(b[3]);
  return r;
}
__device__ __forceinline__ void gld16(void* lds, const void* g){
  __builtin_amdgcn_global_load_lds((const __attribute__((address_space(1))) unsigned int*)g,
                                   (__attribute__((address_space(3))) unsigned int*)lds, 16, 0, 0);
}

// ---------------- X -> bf16 pre-convert --------------------------------------
__global__ __launch_bounds__(256)
void cvtX_kernel(const float* __restrict__ X, ushort* __restrict__ Xbf){
  size_t i = ((size_t)blockIdx.x*256 + threadIdx.x) * 8;
  float4 a = *(const float4*)(X + i);
  float4 b = *(const float4*)(X + i + 4);
  uint2 lo = f4_to_bf4(a), hi = f4_to_bf4(b);
  uint4 o; o.x = lo.x; o.y = lo.y; o.z = hi.x; o.w = hi.y;
  *(uint4*)(Xbf + i) = o;
}

// ---------------- gating (fast): 256 blocks x 16 tokens, fp64 accumulate -----
__global__ __launch_bounds__(256)
void gating_kernel(const float* __restrict__ X, const float* __restrict__ GW,
                   int* __restrict__ topi, float* __restrict__ topw)
{
  __shared__ float xt[16][68];
  __shared__ float gt[64][68];
  __shared__ double ds[16][72];
  const int tid = threadIdx.x;
  const int tbase = blockIdx.x * 16;
  const int t = tid & 15, e0 = (tid >> 4) * 4;
  double acc[4] = {0.0, 0.0, 0.0, 0.0};
  for (int hc=0; hc<HD; hc+=64){
    { int r = tid >> 4, c4 = (tid & 15) * 4;
      *(float4*)&xt[r][c4] = *(const float4*)(X + (size_t)(tbase+r)*HD + hc + c4); }
    #pragma unroll
    for (int it=0; it<4; ++it){
      int idx = it*256 + tid;
      int r = idx >> 4, c4 = (idx & 15) * 4;
      *(float4*)&gt[r][c4] = *(const float4*)(GW + (size_t)r*HD + hc + c4);
    }
    __syncthreads();
    #pragma unroll
    for (int k4=0; k4<16; ++k4){
      float4 xv = *(const float4*)&xt[t][k4*4];
      #pragma unroll
      for (int j=0;j<4;++j){
        float4 gv = *(const float4*)&gt[e0+j][k4*4];
        acc[j] += (double)xv.x*(double)gv.x + (double)xv.y*(double)gv.y
                + (double)xv.z*(double)gv.z + (double)xv.w*(double)gv.w;
      }
    }
    __syncthreads();
  }
  #pragma unroll
  for (int j=0;j<4;++j) ds[t][e0+j] = acc[j];
  __syncthreads();
  if (tid < 16){
    int tt = tid;
    int idxs[8]; double vals[8]; double sum = 0.0;
    #pragma unroll
    for (int k=0;k<8;++k){
      double best = -1e300; int bi = 0;
      for (int e=0;e<NE;++e){ double v = ds[tt][e]; if (v > best){ best = v; bi = e; } }
      ds[tt][bi] = -1e300;
      double w = 1.0 / (1.0 + exp(-best));
      idxs[k] = bi; vals[k] = w; sum += w;
    }
    double inv = 1.0 / sum;
    #pragma unroll
    for (int k=0;k<8;++k){
      topi[(size_t)(tbase+tt)*TK + k] = idxs[k];
      topw[(size_t)(tbase+tt)*TK + k] = (float)(vals[k]*inv);
    }
  }
}

// ---------------- dispatch bookkeeping ---------------------------------------
__global__ __launch_bounds__(256)
void hist_kernel(const int* __restrict__ topi, int* __restrict__ ccnt){
  __shared__ int h[NE];
  const int tid = threadIdx.x;
  if (tid < NE) h[tid] = 0;
  __syncthreads();
  atomicAdd(&h[topi[blockIdx.x*256 + tid]], 1);
  __syncthreads();
  if (tid < NE) ccnt[blockIdx.x*NE + tid] = h[tid];
}

__global__ __launch_bounds__(64)
void scan_kernel(const int* __restrict__ ccnt, int* __restrict__ cbase,
                 int* __restrict__ cntC, int* __restrict__ ebase){
  const int e = threadIdx.x;
  int run = 0;
  for (int c=0;c<NCHUNK;++c){ cbase[c*NE+e] = run; run += ccnt[c*NE+e]; }
  cntC[e] = run < CAP ? run : CAP;
  __syncthreads();
  if (e == 0){
    int s = 0;
    for (int i=0;i<NE;++i){ ebase[i] = s; s += cntC[i]; }
    ebase[NE] = s;
  }
}

__global__ __launch_bounds__(64)
void assign_kernel(const int* __restrict__ topi, const int* __restrict__ cbase,
                   int* __restrict__ pos, int* __restrict__ rowlist){
  __shared__ int es[256];
  const int tid = threadIdx.x;
  const int c = blockIdx.x;
  for (int i=tid;i<256;i+=64) es[i] = topi[c*256+i];
  __syncthreads();
  const int e = tid;
  int cntr = cbase[c*NE+e];
  for (int j=0;j<256;++j){
    if (es[j] == e){
      int n = c*256+j;
      pos[n] = cntr;
      if (cntr < CAP) rowlist[e*CAP + cntr] = n;
      ++cntr;
    }
  }
}

// ---------------- grouped gate/up GEMM + fused SwiGLU (v8: 32x32 frag-order) -
// Block 256 rows x 64 i-cols. 4 waves 2Mx2N; wave = 128 rows x (32g+32u).
// mfma_f32_32x32x16_bf16; LDS tiles staged in MFMA FRAGMENT ORDER via gld16
// (per-lane global source, linear LDS dest) -> all ds_read_b128 stride-1
// across lanes, zero bank conflicts. A bf16 32KB; B fp32 32KB (pack8 at read).
// R4's single-buffer 2-barrier loop; 2 blocks/CU (VGPR-capped anyway).
template<bool SHARED>
__global__ __launch_bounds__(256,2)
void gateup_kernel(const ushort* __restrict__ Xbf, const float* __restrict__ WG,
                   const float* __restrict__ WU, const int* __restrict__ rowlist,
                   const int* __restrict__ cntC, const int* __restrict__ ebase,
                   ushort* __restrict__ interm)
{
  int e, mt, nt, cnt, outbase;
  if (SHARED){
    nt = blockIdx.x & 7; mt = blockIdx.x >> 3; e = 0; cnt = TOK; outbase = mt*256;
  } else {
    int x = blockIdx.x & 7; int rem = blockIdx.x >> 3;
    nt = rem & 7; mt = (rem >> 3) & 3; e = ((rem >> 5) << 3) | x;  // e%8==bid%8 -> XCD locality
    cnt = cntC[e];
    if (mt*256 >= cnt) return;
    outbase = ebase[e] + mt*256;
  }
  const size_t wof = SHARED ? 0 : (size_t)e*ID*HD;
  const float* wg = WG + wof + (size_t)nt*64*HD;
  const float* wu = WU + wof + (size_t)nt*64*HD;

  __shared__ ushort aL[32*64*8];   // 32KB: granule-group G (ks*8+rb) x 64 lanes x 8 bf16
  __shared__ float  bF[32*64*4];   // 32KB: G ((ks*4+mat*2+wn)*2+half) x 64 lanes x 4 f32
  __shared__ int tokb[256];

  const int tid = threadIdx.x;
  {
    int tokv;
    if (SHARED) tokv = mt*256 + tid;
    else tokv = (mt*256 + tid < cnt) ? (rowlist[e*CAP + mt*256 + tid] >> 3) : 0;
    tokb[tid] = tokv;
  }
  __syncthreads();

  const int w = tid >> 6, l = tid & 63;
  const int wm = w >> 1, wn = w & 1;
  const int lr = l & 31, lk = (l >> 5) * 8;   // frag row/col, k-offset

  // A staging sources (fragment order): G = j*4+w = ks*8+rb
  const ushort* aSrc[8];
  #pragma unroll
  for (int j=0;j<8;++j){
    int G = j*4 + w;
    int ks = G >> 3, rb = G & 7;
    aSrc[j] = Xbf + (size_t)tokb[rb*32 + lr]*HD + ks*16 + lk;
  }
  // B staging sources (fragment order): G = j*4+w; half=G&1; q=G>>1: wnb=q&1, mat=(q>>1)&1, ks=q>>2
  const float* bSrc[8];
  #pragma unroll
  for (int j=0;j<8;++j){
    int G = j*4 + w;
    int half = G & 1, q = G >> 1;
    int wnb = q & 1, mat = (q >> 1) & 1, ks = q >> 2;
    const float* base = mat ? wu : wg;
    bSrc[j] = base + (size_t)(wnb*32 + lr)*HD + ks*16 + lk + half*4;
  }

  f32x16 accg[4], accu[4];
  #pragma unroll
  for (int i=0;i<4;++i){ accg[i] = (f32x16)0.0f; accu[i] = (f32x16)0.0f; }

  auto stage = [&](int kc){
    #pragma unroll
    for (int j=0;j<8;++j) gld16(aL + (size_t)(j*256 + w*64)*8, aSrc[j] + kc);
    #pragma unroll
    for (int j=0;j<8;++j) gld16(bF + (size_t)(j*256 + w*64)*4, bSrc[j] + kc);
  };

  stage(0);
  for (int kc=0; kc<HD; kc+=64){
    __syncthreads();   // drains vmcnt: staged tile visible
    #pragma unroll
    for (int ks=0; ks<4; ++ks){
      s16x8 a[4];
      #pragma unroll
      for (int rb=0; rb<4; ++rb){
        int G = ks*8 + wm*4 + rb;
        a[rb] = *(const s16x8*)&aL[(G*64 + l)*8];
      }
      int qg = ks*4 + wn;          // mat=0
      int qu = ks*4 + 2 + wn;      // mat=1
      s16x8 bg = pack8(*(const f32x4*)&bF[(qg*2*64 + l)*4],
                       *(const f32x4*)&bF[((qg*2+1)*64 + l)*4]);
      s16x8 bu = pack8(*(const f32x4*)&bF[(qu*2*64 + l)*4],
                       *(const f32x4*)&bF[((qu*2+1)*64 + l)*4]);
      #pragma unroll
      for (int rb=0; rb<4; ++rb){
        accg[rb] = __builtin_amdgcn_mfma_f32_32x32x16_bf16(a[rb], bg, accg[rb], 0, 0, 0);
        accu[rb] = __builtin_amdgcn_mfma_f32_32x32x16_bf16(a[rb], bu, accu[rb], 0, 0, 0);
      }
    }
    __syncthreads();
    if (kc + 64 < HD) stage(kc + 64);
  }

  // epilogue: C/D layout col=l&31, row=(reg&3)+8*(reg>>2)+4*(l>>5)
  #pragma unroll
  for (int rb=0; rb<4; ++rb){
    #pragma unroll
    for (int r=0; r<16; ++r){
      int rowl = (r & 3) + 8*(r >> 2) + 4*(l >> 5);
      int rloc = wm*128 + rb*32 + rowl;
      if (!SHARED && mt*256 + rloc >= cnt) continue;
      float g = accg[rb][r], u = accu[rb][r];
      float sv = g / (1.0f + __expf(-g)) * u;   // silu(g)*u
      interm[(size_t)(outbase + rloc)*ID + nt*64 + wn*32 + lr] = f2bf(sv);
    }
  }
}

// ---------------- grouped down GEMM (v8: 32x32 frag-order) -------------------
// Block 256 rows x 128 out-cols. 4 waves 2Mx2N; wave = 128 x 64. K=512.
template<bool SHARED>
__global__ __launch_bounds__(256,2)
void down_kernel(const ushort* __restrict__ interm, const float* __restrict__ WD,
                 const int* __restrict__ cntC, const int* __restrict__ ebase,
                 ushort* __restrict__ out_rows, float* __restrict__ outf)
{
  int e, mt, nt, cnt, abase;
  if (SHARED){
    nt = blockIdx.x & 7; mt = blockIdx.x >> 3; e = 0; cnt = TOK; abase = mt*256;
  } else {
    int x = blockIdx.x & 7; int rem = blockIdx.x >> 3;
    nt = rem & 7; mt = (rem >> 3) & 3; e = ((rem >> 5) << 3) | x;
    cnt = cntC[e];
    if (mt*256 >= cnt) return;
    abase = ebase[e] + mt*256;
  }
  const ushort* A = interm + (size_t)abase*ID;
  const float* wd = WD + (SHARED ? (size_t)0 : (size_t)e*HD*ID) + (size_t)nt*128*ID;

  __shared__ ushort aL[32*64*8];   // 32KB frag-order A
  __shared__ float  bF[32*64*4];   // 32KB frag-order B: G=(ks*4+cf)*2+half

  const int tid = threadIdx.x;
  const int w = tid >> 6, l = tid & 63;
  const int wm = w >> 1, wn = w & 1;
  const int lr = l & 31, lk = (l >> 5) * 8;

  const ushort* aSrc[8];
  #pragma unroll
  for (int j=0;j<8;++j){
    int G = j*4 + w;
    int ks = G >> 3, rb = G & 7;
    aSrc[j] = A + (size_t)(rb*32 + lr)*ID + ks*16 + lk;
  }
  const float* bSrc[8];
  #pragma unroll
  for (int j=0;j<8;++j){
    int G = j*4 + w;
    int half = G & 1, q = G >> 1;
    int cf = q & 3, ks = q >> 2;
    bSrc[j] = wd + (size_t)(cf*32 + lr)*ID + ks*16 + lk + half*4;
  }

  f32x16 acc[4][2];
  #pragma unroll
  for (int i=0;i<4;++i)
    #pragma unroll
    for (int jx=0;jx<2;++jx) acc[i][jx] = (f32x16)0.0f;

  auto stage = [&](int kc){
    #pragma unroll
    for (int j=0;j<8;++j) gld16(aL + (size_t)(j*256 + w*64)*8, aSrc[j] + kc);
    #pragma unroll
    for (int j=0;j<8;++j) gld16(bF + (size_t)(j*256 + w*64)*4, bSrc[j] + kc);
  };

  stage(0);
  for (int kc=0; kc<ID; kc+=64){
    __syncthreads();
    #pragma unroll
    for (int ks=0; ks<4; ++ks){
      s16x8 a[4];
      #pragma unroll
      for (int rb=0; rb<4; ++rb){
        int G = ks*8 + wm*4 + rb;
        a[rb] = *(const s16x8*)&aL[(G*64 + l)*8];
      }
      #pragma unroll
      for (int cg=0; cg<2; ++cg){
        int q = ks*4 + wn*2 + cg;
        s16x8 bd = pack8(*(const f32x4*)&bF[(q*2*64 + l)*4],
                         *(const f32x4*)&bF[((q*2+1)*64 + l)*4]);
        #pragma unroll
        for (int rb=0; rb<4; ++rb)
          acc[rb][cg] = __builtin_amdgcn_mfma_f32_32x32x16_bf16(a[rb], bd, acc[rb][cg], 0, 0, 0);
      }
    }
    __syncthreads();
    if (kc + 64 < ID) stage(kc + 64);
  }

  #pragma unroll
  for (int rb=0; rb<4; ++rb){
    #pragma unroll
    for (int cg=0; cg<2; ++cg){
      #pragma unroll
      for (int r=0; r<16; ++r){
        int rowl = (r & 3) + 8*(r >> 2) + 4*(l >> 5);
        int rloc = wm*128 + rb*32 + rowl;
        if (!SHARED && mt*256 + rloc >= cnt) continue;
        float v = acc[rb][cg][r];
        int colg = nt*128 + wn*64 + cg*32 + lr;
        if (SHARED) outf[(size_t)(mt*256 + rloc)*HD + colg] = v;
        else        out_rows[(size_t)(abase + rloc)*HD + colg] = f2bf(v);
      }
    }
  }
}

// ---------------- combine: out += sum_k topw * routed_row --------------------
__global__ __launch_bounds__(256)
void combine_kernel(const int* __restrict__ topi, const float* __restrict__ topw,
                    const int* __restrict__ pos, const int* __restrict__ ebase,
                    const ushort* __restrict__ out_rows, float* __restrict__ out)
{
  const int t = blockIdx.x;
  const int tid = threadIdx.x;
  __shared__ int rws[TK];
  __shared__ float wts[TK];
  if (tid < TK){
    int e = topi[(size_t)t*TK + tid];
    int p = pos[(size_t)t*TK + tid];
    rws[tid] = (p < CAP) ? (ebase[e] + p) : -1;
    wts[tid] = topw[(size_t)t*TK + tid];
  }
  __syncthreads();
  const int h0 = tid * 4;
  float4 acc = *(float4*)(out + (size_t)t*HD + h0);
  #pragma unroll
  for (int k=0;k<TK;++k){
    int r = rws[k];
    if (r < 0) continue;
    ushort4 v = *(const ushort4*)(out_rows + (size_t)r*HD + h0);
    float wk = wts[k];
    acc.x += wk*bf2f(v.x); acc.y += wk*bf2f(v.y);
    acc.z += wk*bf2f(v.z); acc.w += wk*bf2f(v.w);
  }
  *(float4*)(out + (size_t)t*HD + h0) = acc;
}

// ---------------- launch ------------------------------------------------------
extern "C" void kernel_launch(void* const* d_in, const int* in_sizes, int n_in,
                              void* d_out, int out_size, void* d_ws, size_t ws_size,
                              hipStream_t stream)
{
  (void)in_sizes; (void)n_in; (void)out_size; (void)ws_size;
  const float* X   = (const float*)d_in[0];
  const float* GW  = (const float*)d_in[1];
  const float* SWG = (const float*)d_in[2];
  const float* SWU = (const float*)d_in[3];
  const float* SWD = (const float*)d_in[4];
  const float* EWG = (const float*)d_in[5];
  const float* EWU = (const float*)d_in[6];
  const float* EWD = (const float*)d_in[7];
  float* OUT = (float*)d_out;

  char* p = (char*)d_ws;
  int*    topi    = (int*)p;      p += (size_t)NROUTE*4;
  float*  topw    = (float*)p;    p += (size_t)NROUTE*4;
  int*    pos     = (int*)p;      p += (size_t)NROUTE*4;
  int*    ccnt    = (int*)p;      p += (size_t)NCHUNK*NE*4;
  int*    cbase   = (int*)p;      p += (size_t)NCHUNK*NE*4;
  int*    cntC    = (int*)p;      p += 256;
  int*    ebase   = (int*)p;      p += 512;
  int*    rowlist = (int*)p;      p += (size_t)NE*CAP*4;
  ushort* Xbf     = (ushort*)p;   p += (size_t)TOK*HD*2;
  ushort* interm_r= (ushort*)p;   p += (size_t)(NROUTE+256)*ID*2;
  ushort* interm_s= (ushort*)p;   p += (size_t)TOK*ID*2;
  ushort* out_rows= (ushort*)p;   p += (size_t)NROUTE*HD*2;

  cvtX_kernel<<<TOK*HD/8/256, 256, 0, stream>>>(X, Xbf);
  gating_kernel<<<256, 256, 0, stream>>>(X, GW, topi, topw);
  hist_kernel<<<NCHUNK, 256, 0, stream>>>(topi, ccnt);
  scan_kernel<<<1, 64, 0, stream>>>(ccnt, cbase, cntC, ebase);
  assign_kernel<<<NCHUNK, 64, 0, stream>>>(topi, cbase, pos, rowlist);

  gateup_kernel<false><<<2048, 256, 0, stream>>>(Xbf, EWG, EWU, rowlist, cntC, ebase, interm_r);
  gateup_kernel<true ><<<128,  256, 0, stream>>>(Xbf, SWG, SWU, nullptr, nullptr, nullptr, interm_s);
  down_kernel<false><<<2048, 256, 0, stream>>>(interm_r, EWD, cntC, ebase, out_rows, nullptr);
  down_kernel<true ><<<128,  256, 0, stream>>>(interm_s, SWD, nullptr, nullptr, nullptr, OUT);

  combine_kernel<<<TOK, 256, 0, stream>>>(topi, topw, pos, ebase, out_rows, OUT);
}

// Round 13
// 436.884 us; speedup vs baseline: 1.3219x; 1.3219x over previous
//
#include <hip/hip_runtime.h>
#include <hip/hip_bf16.h>

#define TOK 4096
#define HD 1024
#define ID 512
#define NE 64
#define TK 8
#define CAP 1024
#define NROUTE 32768   // TOK*TK
#define NCHUNK 128     // NROUTE/256

typedef __attribute__((ext_vector_type(4))) float f32x4;
typedef __attribute__((ext_vector_type(8))) short s16x8;
typedef __attribute__((ext_vector_type(2))) __bf16 bf16x2;

__device__ __forceinline__ ushort f2bf(float f){
  uint u = __builtin_bit_cast(uint, f);
  u += 0x7fffu + ((u >> 16) & 1u);
  return (ushort)(u >> 16);
}
__device__ __forceinline__ float bf2f(ushort b){
  uint u = ((uint)b) << 16;
  return __builtin_bit_cast(float, u);
}
__device__ __forceinline__ uint2 f4_to_bf4(float4 v){
  bf16x2 p0; p0[0] = (__bf16)v.x; p0[1] = (__bf16)v.y;
  bf16x2 p1; p1[0] = (__bf16)v.z; p1[1] = (__bf16)v.w;
  uint2 r; r.x = __builtin_bit_cast(uint, p0); r.y = __builtin_bit_cast(uint, p1);
  return r;
}
__device__ __forceinline__ short bfs(float f){
  __bf16 h = (__bf16)f;
  return __builtin_bit_cast(short, h);
}
__device__ __forceinline__ s16x8 pack8(float4 a, float4 b){
  s16x8 r;
  r[0]=bfs(a.x); r[1]=bfs(a.y); r[2]=bfs(a.z); r[3]=bfs(a.w);
  r[4]=bfs(b.x); r[5]=bfs(b.y); r[6]=bfs(b.z); r[7]=bfs(b.w);
  return r;
}
__device__ __forceinline__ void gld16(void* lds, const void* g){
  __builtin_amdgcn_global_load_lds((const __attribute__((address_space(1))) unsigned int*)g,
                                   (__attribute__((address_space(3))) unsigned int*)lds, 16, 0, 0);
}

// ---------------- X -> bf16 pre-convert --------------------------------------
__global__ __launch_bounds__(256)
void cvtX_kernel(const float* __restrict__ X, ushort* __restrict__ Xbf){
  size_t i = ((size_t)blockIdx.x*256 + threadIdx.x) * 8;
  float4 a = *(const float4*)(X + i);
  float4 b = *(const float4*)(X + i + 4);
  uint2 lo = f4_to_bf4(a), hi = f4_to_bf4(b);
  uint4 o; o.x = lo.x; o.y = lo.y; o.z = hi.x; o.w = hi.y;
  *(uint4*)(Xbf + i) = o;
}

// ---------------- gating (fast): 256 blocks x 16 tokens, fp64 accumulate -----
__global__ __launch_bounds__(256)
void gating_kernel(const float* __restrict__ X, const float* __restrict__ GW,
                   int* __restrict__ topi, float* __restrict__ topw)
{
  __shared__ float xt[16][68];
  __shared__ float gt[64][68];
  __shared__ double ds[16][72];
  const int tid = threadIdx.x;
  const int tbase = blockIdx.x * 16;
  const int t = tid & 15, e0 = (tid >> 4) * 4;
  double acc[4] = {0.0, 0.0, 0.0, 0.0};
  for (int hc=0; hc<HD; hc+=64){
    { int r = tid >> 4, c4 = (tid & 15) * 4;
      *(float4*)&xt[r][c4] = *(const float4*)(X + (size_t)(tbase+r)*HD + hc + c4); }
    #pragma unroll
    for (int it=0; it<4; ++it){
      int idx = it*256 + tid;
      int r = idx >> 4, c4 = (idx & 15) * 4;
      *(float4*)&gt[r][c4] = *(const float4*)(GW + (size_t)r*HD + hc + c4);
    }
    __syncthreads();
    #pragma unroll
    for (int k4=0; k4<16; ++k4){
      float4 xv = *(const float4*)&xt[t][k4*4];
      #pragma unroll
      for (int j=0;j<4;++j){
        float4 gv = *(const float4*)&gt[e0+j][k4*4];
        acc[j] += (double)xv.x*(double)gv.x + (double)xv.y*(double)gv.y
                + (double)xv.z*(double)gv.z + (double)xv.w*(double)gv.w;
      }
    }
    __syncthreads();
  }
  #pragma unroll
  for (int j=0;j<4;++j) ds[t][e0+j] = acc[j];
  __syncthreads();
  if (tid < 16){
    int tt = tid;
    int idxs[8]; double vals[8]; double sum = 0.0;
    #pragma unroll
    for (int k=0;k<8;++k){
      double best = -1e300; int bi = 0;
      for (int e=0;e<NE;++e){ double v = ds[tt][e]; if (v > best){ best = v; bi = e; } }
      ds[tt][bi] = -1e300;
      double w = 1.0 / (1.0 + exp(-best));
      idxs[k] = bi; vals[k] = w; sum += w;
    }
    double inv = 1.0 / sum;
    #pragma unroll
    for (int k=0;k<8;++k){
      topi[(size_t)(tbase+tt)*TK + k] = idxs[k];
      topw[(size_t)(tbase+tt)*TK + k] = (float)(vals[k]*inv);
    }
  }
}

// ---------------- dispatch bookkeeping ---------------------------------------
__global__ __launch_bounds__(256)
void hist_kernel(const int* __restrict__ topi, int* __restrict__ ccnt){
  __shared__ int h[NE];
  const int tid = threadIdx.x;
  if (tid < NE) h[tid] = 0;
  __syncthreads();
  atomicAdd(&h[topi[blockIdx.x*256 + tid]], 1);
  __syncthreads();
  if (tid < NE) ccnt[blockIdx.x*NE + tid] = h[tid];
}

__global__ __launch_bounds__(64)
void scan_kernel(const int* __restrict__ ccnt, int* __restrict__ cbase,
                 int* __restrict__ cntC, int* __restrict__ ebase){
  const int e = threadIdx.x;
  int run = 0;
  for (int c=0;c<NCHUNK;++c){ cbase[c*NE+e] = run; run += ccnt[c*NE+e]; }
  cntC[e] = run < CAP ? run : CAP;
  __syncthreads();
  if (e == 0){
    int s = 0;
    for (int i=0;i<NE;++i){ ebase[i] = s; s += cntC[i]; }
    ebase[NE] = s;
  }
}

__global__ __launch_bounds__(64)
void assign_kernel(const int* __restrict__ topi, const int* __restrict__ cbase,
                   int* __restrict__ pos, int* __restrict__ rowlist){
  __shared__ int es[256];
  const int tid = threadIdx.x;
  const int c = blockIdx.x;
  for (int i=tid;i<256;i+=64) es[i] = topi[c*256+i];
  __syncthreads();
  const int e = tid;
  int cntr = cbase[c*NE+e];
  for (int j=0;j<256;++j){
    if (es[j] == e){
      int n = c*256+j;
      pos[n] = cntr;
      if (cntr < CAP) rowlist[e*CAP + cntr] = n;
      ++cntr;
    }
  }
}

// ---------------- grouped gate/up GEMM + fused SwiGLU (v9) -------------------
// R10 structure, B in LDS as bf16 via reg-stage. Block 128 rows x 64 i-cols,
// 4 waves 2x2; wave = 64 rows x (32g+32u). A: bf16 gld16 (16KB). B: bf16
// (16KB), loadB(t+1) issued at top of compute(t) -> latency hidden; writeB
// after barrier. Both tiles 2-row-line 16-slot XOR. 33.8KB LDS -> 4 blocks/CU.
template<bool SHARED>
__global__ __launch_bounds__(256,2)
void gateup_kernel(const ushort* __restrict__ Xbf, const float* __restrict__ WG,
                   const float* __restrict__ WU, const int* __restrict__ rowlist,
                   const int* __restrict__ cntC, const int* __restrict__ ebase,
                   ushort* __restrict__ interm)
{
  int e, mt, nt, cnt, outbase;
  if (SHARED){
    nt = blockIdx.x & 7; mt = blockIdx.x >> 3; e = 0; cnt = TOK; outbase = mt*128;
  } else {
    int x = blockIdx.x & 7; int rem = blockIdx.x >> 3;
    nt = rem & 7; mt = (rem >> 3) & 7; e = ((rem >> 6) << 3) | x;  // e%8==bid%8 -> XCD locality
    cnt = cntC[e];
    if (mt*128 >= cnt) return;
    outbase = ebase[e] + mt*128;
  }
  const size_t wof = SHARED ? 0 : (size_t)e*ID*HD;
  const float* wg = WG + wof + (size_t)nt*64*HD;
  const float* wu = WU + wof + (size_t)nt*64*HD;

  __shared__ ushort aL[64*128];   // 16KB: 64 lines (=128 rows) x 16 granules
  __shared__ ushort bB[64*128];   // 16KB bf16: rows 0-63 gate, 64-127 up
  __shared__ int tokb[128];

  const int tid = threadIdx.x;
  if (tid < 128){
    int tokv;
    if (SHARED) tokv = mt*128 + tid;
    else tokv = (mt*128 + tid < cnt) ? (rowlist[e*CAP + mt*128 + tid] >> 3) : 0;
    tokb[tid] = tokv;
  }
  __syncthreads();

  const int w = tid >> 6, l = tid & 63;
  const int wm = w >> 1, wn = w & 1;
  const int fr = l & 15, fko = (l >> 4) * 8;

  // A staging sources: inverse-swizzled global addresses (4 gld16/thread)
  const ushort* aSrc[4];
  #pragma unroll
  for (int j=0;j<4;++j){
    int f = j*256 + tid;
    int L = f >> 4, s = f & 15;
    int g = s ^ (L & 15);
    int row = 2*L + (g >> 3);
    aSrc[j] = Xbf + (size_t)tokb[row]*HD + (g & 7)*8;
  }
  // B staging: 4 granules/thread, reg->cvt->ds_write at linear (swizzle in src)
  const float* bSrc[4]; int bDst[4];
  #pragma unroll
  for (int i=0;i<4;++i){
    int f = i*256 + tid;
    int L = f >> 4, s = f & 15;
    int g = s ^ (L & 15);
    int brow = 2*L + (g >> 3);           // 0..127
    int gk = g & 7;
    bSrc[i] = ((brow < 64) ? (wg + (size_t)brow*HD) : (wu + (size_t)(brow-64)*HD)) + gk*8;
    bDst[i] = f*8;
  }

  f32x4 accg[4][2], accu[4][2];
  #pragma unroll
  for (int i=0;i<4;++i)
    #pragma unroll
    for (int j=0;j<2;++j){ accg[i][j] = (f32x4)0.0f; accu[i][j] = (f32x4)0.0f; }

  float4 brv[8];
  auto loadB = [&](int kc){
    #pragma unroll
    for (int i=0;i<4;++i){
      brv[2*i]   = *(const float4*)(bSrc[i] + kc);
      brv[2*i+1] = *(const float4*)(bSrc[i] + kc + 4);
    }
  };
  auto writeB = [&](){
    #pragma unroll
    for (int i=0;i<4;++i) *(s16x8*)&bB[bDst[i]] = pack8(brv[2*i], brv[2*i+1]);
  };
  auto stageA = [&](int kc){
    #pragma unroll
    for (int j=0;j<4;++j) gld16(aL + (size_t)(j*256 + w*64)*8, aSrc[j] + kc);
  };

  // prologue: tile 0 fully staged
  loadB(0); stageA(0); writeB();
  __syncthreads();

  for (int t=0; t<16; ++t){
    const int kc = t*64;
    if (t < 15) loadB(kc + 64);          // issue next-tile B loads before compute
    #pragma unroll
    for (int ks=0; ks<2; ++ks){
      int gk = ks*4 + (fko >> 3);
      s16x8 a[4];
      #pragma unroll
      for (int mb=0; mb<4; ++mb){
        int r = wm*64 + mb*16 + fr;
        int g = ((r & 1) << 3) | gk;
        int L = r >> 1;
        a[mb] = *(const s16x8*)&aL[L*128 + ((g ^ (L & 15)))*8];
      }
      #pragma unroll
      for (int cg=0; cg<2; ++cg){
        int Rg = wn*32 + cg*16 + fr;
        int Lg = Rg >> 1, gg = ((Rg & 1) << 3) | gk;
        s16x8 bg = *(const s16x8*)&bB[Lg*128 + ((gg ^ (Lg & 15)))*8];
        int Ru = 64 + wn*32 + cg*16 + fr;
        int Lu = Ru >> 1, gu = ((Ru & 1) << 3) | gk;
        s16x8 bu = *(const s16x8*)&bB[Lu*128 + ((gu ^ (Lu & 15)))*8];
        #pragma unroll
        for (int mb=0; mb<4; ++mb){
          accg[mb][cg] = __builtin_amdgcn_mfma_f32_16x16x32_bf16(a[mb], bg, accg[mb][cg], 0, 0, 0);
          accu[mb][cg] = __builtin_amdgcn_mfma_f32_16x16x32_bf16(a[mb], bu, accu[mb][cg], 0, 0, 0);
        }
      }
    }
    __syncthreads();                     // all waves done reading aL/bB
    if (t < 15){ writeB(); stageA(kc + 64); }
    __syncthreads();                     // staged tile visible (drains A gld16)
  }

  const int rq = (l >> 4) * 4;
  #pragma unroll
  for (int mb=0; mb<4; ++mb){
    #pragma unroll
    for (int q=0; q<4; ++q){
      int rloc = wm*64 + mb*16 + rq + q;
      if (!SHARED && mt*128 + rloc >= cnt) continue;
      size_t orow = (size_t)(outbase + rloc);
      #pragma unroll
      for (int cg=0; cg<2; ++cg){
        float g = accg[mb][cg][q], u = accu[mb][cg][q];
        float sv = g / (1.0f + __expf(-g)) * u;   // silu(g)*u
        interm[orow*ID + (size_t)(nt*64 + wn*32 + cg*16 + fr)] = f2bf(sv);
      }
    }
  }
}

// ---------------- grouped down GEMM (v9) -------------------------------------
// Block 128 rows x 128 out-cols, 4 waves 2x2; wave = 64 x 64. B bf16 reg-staged.
template<bool SHARED>
__global__ __launch_bounds__(256,2)
void down_kernel(const ushort* __restrict__ interm, const float* __restrict__ WD,
                 const int* __restrict__ cntC, const int* __restrict__ ebase,
                 ushort* __restrict__ out_rows, float* __restrict__ outf)
{
  int e, mt, nt, cnt, abase;
  if (SHARED){
    nt = blockIdx.x & 7; mt = blockIdx.x >> 3; e = 0; cnt = TOK; abase = mt*128;
  } else {
    int x = blockIdx.x & 7; int rem = blockIdx.x >> 3;
    nt = rem & 7; mt = (rem >> 3) & 7; e = ((rem >> 6) << 3) | x;
    cnt = cntC[e];
    if (mt*128 >= cnt) return;
    abase = ebase[e] + mt*128;
  }
  const ushort* A = interm + (size_t)abase*ID;
  const float* wd = WD + (SHARED ? (size_t)0 : (size_t)e*HD*ID) + (size_t)nt*128*ID;

  __shared__ ushort aL[64*128];   // 16KB
  __shared__ ushort bB[64*128];   // 16KB bf16: 128 out-col rows

  const int tid = threadIdx.x;
  const int w = tid >> 6, l = tid & 63;
  const int wm = w >> 1, wn = w & 1;
  const int fr = l & 15, fko = (l >> 4) * 8;

  const ushort* aSrc[4];
  #pragma unroll
  for (int j=0;j<4;++j){
    int f = j*256 + tid;
    int L = f >> 4, s = f & 15;
    int g = s ^ (L & 15);
    int row = 2*L + (g >> 3);
    aSrc[j] = A + (size_t)row*ID + (g & 7)*8;
  }
  const float* bSrc[4]; int bDst[4];
  #pragma unroll
  for (int i=0;i<4;++i){
    int f = i*256 + tid;
    int L = f >> 4, s = f & 15;
    int g = s ^ (L & 15);
    int brow = 2*L + (g >> 3);           // 0..127 out-col
    int gk = g & 7;
    bSrc[i] = wd + (size_t)brow*ID + gk*8;
    bDst[i] = f*8;
  }

  f32x4 acc[4][4];
  #pragma unroll
  for (int i=0;i<4;++i)
    #pragma unroll
    for (int j=0;j<4;++j) acc[i][j] = (f32x4)0.0f;

  float4 brv[8];
  auto loadB = [&](int kc){
    #pragma unroll
    for (int i=0;i<4;++i){
      brv[2*i]   = *(const float4*)(bSrc[i] + kc);
      brv[2*i+1] = *(const float4*)(bSrc[i] + kc + 4);
    }
  };
  auto writeB = [&](){
    #pragma unroll
    for (int i=0;i<4;++i) *(s16x8*)&bB[bDst[i]] = pack8(brv[2*i], brv[2*i+1]);
  };
  auto stageA = [&](int kc){
    #pragma unroll
    for (int j=0;j<4;++j) gld16(aL + (size_t)(j*256 + w*64)*8, aSrc[j] + kc);
  };

  loadB(0); stageA(0); writeB();
  __syncthreads();

  for (int t=0; t<8; ++t){
    const int kc = t*64;
    if (t < 7) loadB(kc + 64);
    #pragma unroll
    for (int ks=0; ks<2; ++ks){
      int gk = ks*4 + (fko >> 3);
      s16x8 a[4];
      #pragma unroll
      for (int mb=0; mb<4; ++mb){
        int r = wm*64 + mb*16 + fr;
        int g = ((r & 1) << 3) | gk;
        int L = r >> 1;
        a[mb] = *(const s16x8*)&aL[L*128 + ((g ^ (L & 15)))*8];
      }
      #pragma unroll
      for (int cg=0; cg<4; ++cg){
        int R = wn*64 + cg*16 + fr;
        int L = R >> 1, g = ((R & 1) << 3) | gk;
        s16x8 bd = *(const s16x8*)&bB[L*128 + ((g ^ (L & 15)))*8];
        #pragma unroll
        for (int mb=0; mb<4; ++mb){
          acc[mb][cg] = __builtin_amdgcn_mfma_f32_16x16x32_bf16(a[mb], bd, acc[mb][cg], 0, 0, 0);
        }
      }
    }
    __syncthreads();
    if (t < 7){ writeB(); stageA(kc + 64); }
    __syncthreads();
  }

  const int rq = (l >> 4) * 4;
  #pragma unroll
  for (int mb=0; mb<4; ++mb){
    #pragma unroll
    for (int q=0; q<4; ++q){
      int rloc = wm*64 + mb*16 + rq + q;
      if (!SHARED && mt*128 + rloc >= cnt) continue;
      #pragma unroll
      for (int cg=0; cg<4; ++cg){
        float v = acc[mb][cg][q];
        int colg = nt*128 + wn*64 + cg*16 + fr;
        if (SHARED) outf[(size_t)(mt*128 + rloc)*HD + colg] = v;
        else        out_rows[(size_t)(abase + rloc)*HD + colg] = f2bf(v);
      }
    }
  }
}

// ---------------- combine: out += sum_k topw * routed_row --------------------
__global__ __launch_bounds__(256)
void combine_kernel(const int* __restrict__ topi, const float* __restrict__ topw,
                    const int* __restrict__ pos, const int* __restrict__ ebase,
                    const ushort* __restrict__ out_rows, float* __restrict__ out)
{
  const int t = blockIdx.x;
  const int tid = threadIdx.x;
  __shared__ int rws[TK];
  __shared__ float wts[TK];
  if (tid < TK){
    int e = topi[(size_t)t*TK + tid];
    int p = pos[(size_t)t*TK + tid];
    rws[tid] = (p < CAP) ? (ebase[e] + p) : -1;
    wts[tid] = topw[(size_t)t*TK + tid];
  }
  __syncthreads();
  const int h0 = tid * 4;
  float4 acc = *(float4*)(out + (size_t)t*HD + h0);
  #pragma unroll
  for (int k=0;k<TK;++k){
    int r = rws[k];
    if (r < 0) continue;
    ushort4 v = *(const ushort4*)(out_rows + (size_t)r*HD + h0);
    float wk = wts[k];
    acc.x += wk*bf2f(v.x); acc.y += wk*bf2f(v.y);
    acc.z += wk*bf2f(v.z); acc.w += wk*bf2f(v.w);
  }
  *(float4*)(out + (size_t)t*HD + h0) = acc;
}

// ---------------- launch ------------------------------------------------------
extern "C" void kernel_launch(void* const* d_in, const int* in_sizes, int n_in,
                              void* d_out, int out_size, void* d_ws, size_t ws_size,
                              hipStream_t stream)
{
  (void)in_sizes; (void)n_in; (void)out_size; (void)ws_size;
  const float* X   = (const float*)d_in[0];
  const float* GW  = (const float*)d_in[1];
  const float* SWG = (const float*)d_in[2];
  const float* SWU = (const float*)d_in[3];
  const float* SWD = (const float*)d_in[4];
  const float* EWG = (const float*)d_in[5];
  const float* EWU = (const float*)d_in[6];
  const float* EWD = (const float*)d_in[7];
  float* OUT = (float*)d_out;

  char* p = (char*)d_ws;
  int*    topi    = (int*)p;      p += (size_t)NROUTE*4;
  float*  topw    = (float*)p;    p += (size_t)NROUTE*4;
  int*    pos     = (int*)p;      p += (size_t)NROUTE*4;
  int*    ccnt    = (int*)p;      p += (size_t)NCHUNK*NE*4;
  int*    cbase   = (int*)p;      p += (size_t)NCHUNK*NE*4;
  int*    cntC    = (int*)p;      p += 256;
  int*    ebase   = (int*)p;      p += 512;
  int*    rowlist = (int*)p;      p += (size_t)NE*CAP*4;
  ushort* Xbf     = (ushort*)p;   p += (size_t)TOK*HD*2;
  ushort* interm_r= (ushort*)p;   p += (size_t)(NROUTE+128)*ID*2;
  ushort* interm_s= (ushort*)p;   p += (size_t)TOK*ID*2;
  ushort* out_rows= (ushort*)p;   p += (size_t)NROUTE*HD*2;

  cvtX_kernel<<<TOK*HD/8/256, 256, 0, stream>>>(X, Xbf);
  gating_kernel<<<256, 256, 0, stream>>>(X, GW, topi, topw);
  hist_kernel<<<NCHUNK, 256, 0, stream>>>(topi, ccnt);
  scan_kernel<<<1, 64, 0, stream>>>(ccnt, cbase, cntC, ebase);
  assign_kernel<<<NCHUNK, 64, 0, stream>>>(topi, cbase, pos, rowlist);

  gateup_kernel<false><<<4096, 256, 0, stream>>>(Xbf, EWG, EWU, rowlist, cntC, ebase, interm_r);
  gateup_kernel<true ><<<256,  256, 0, stream>>>(Xbf, SWG, SWU, nullptr, nullptr, nullptr, interm_s);
  down_kernel<false><<<4096, 256, 0, stream>>>(interm_r, EWD, cntC, ebase, out_rows, nullptr);
  down_kernel<true ><<<256,  256, 0, stream>>>(interm_s, SWD, nullptr, nullptr, nullptr, OUT);

  combine_kernel<<<TOK, 256, 0, stream>>>(topi, topw, pos, ebase, out_rows, OUT);
}

// Round 14
// 361.245 us; speedup vs baseline: 1.5987x; 1.2094x over previous
//
#include <hip/hip_runtime.h>
#include <hip/hip_bf16.h>

#define TOK 4096
#define HD 1024
#define ID 512
#define NE 64
#define TK 8
#define CAP 1024
#define NROUTE 32768   // TOK*TK
#define NCHUNK 128     // NROUTE/256

typedef __attribute__((ext_vector_type(4))) float f32x4;
typedef __attribute__((ext_vector_type(8))) short s16x8;
typedef __attribute__((ext_vector_type(2))) __bf16 bf16x2;

__device__ __forceinline__ ushort f2bf(float f){
  uint u = __builtin_bit_cast(uint, f);
  u += 0x7fffu + ((u >> 16) & 1u);
  return (ushort)(u >> 16);
}
__device__ __forceinline__ float bf2f(ushort b){
  uint u = ((uint)b) << 16;
  return __builtin_bit_cast(float, u);
}
__device__ __forceinline__ uint2 f4_to_bf4(float4 v){
  bf16x2 p0; p0[0] = (__bf16)v.x; p0[1] = (__bf16)v.y;
  bf16x2 p1; p1[0] = (__bf16)v.z; p1[1] = (__bf16)v.w;
  uint2 r; r.x = __builtin_bit_cast(uint, p0); r.y = __builtin_bit_cast(uint, p1);
  return r;
}
__device__ __forceinline__ short bfs(float f){
  __bf16 h = (__bf16)f;
  return __builtin_bit_cast(short, h);
}
__device__ __forceinline__ s16x8 pack8(f32x4 a, f32x4 b){
  s16x8 r;
  r[0]=bfs(a[0]); r[1]=bfs(a[1]); r[2]=bfs(a[2]); r[3]=bfs(a[3]);
  r[4]=bfs(b[0]); r[5]=bfs(b[1]); r[6]=bfs(b[2]); r[7]=bfs(b[3]);
  return r;
}
__device__ __forceinline__ void gld16(void* lds, const void* g){
  __builtin_amdgcn_global_load_lds((const __attribute__((address_space(1))) unsigned int*)g,
                                   (__attribute__((address_space(3))) unsigned int*)lds, 16, 0, 0);
}

// ---------------- gating + X->bf16 byproduct ---------------------------------
// 256 blocks x 16 tokens; fp64 accumulate; writes Xbf while staging X.
__global__ __launch_bounds__(256)
void gating_kernel(const float* __restrict__ X, const float* __restrict__ GW,
                   ushort* __restrict__ Xbf,
                   int* __restrict__ topi, float* __restrict__ topw)
{
  __shared__ float xt[16][68];
  __shared__ float gt[64][68];
  __shared__ double ds[16][72];
  const int tid = threadIdx.x;
  const int tbase = blockIdx.x * 16;
  const int t = tid & 15, e0 = (tid >> 4) * 4;
  double acc[4] = {0.0, 0.0, 0.0, 0.0};
  for (int hc=0; hc<HD; hc+=64){
    { int r = tid >> 4, c4 = (tid & 15) * 4;
      float4 v = *(const float4*)(X + (size_t)(tbase+r)*HD + hc + c4);
      *(float4*)&xt[r][c4] = v;
      *(uint2*)(Xbf + (size_t)(tbase+r)*HD + hc + c4) = f4_to_bf4(v);   // fused cvtX
    }
    #pragma unroll
    for (int it=0; it<4; ++it){
      int idx = it*256 + tid;
      int r = idx >> 4, c4 = (idx & 15) * 4;
      *(float4*)&gt[r][c4] = *(const float4*)(GW + (size_t)r*HD + hc + c4);
    }
    __syncthreads();
    #pragma unroll
    for (int k4=0; k4<16; ++k4){
      float4 xv = *(const float4*)&xt[t][k4*4];
      #pragma unroll
      for (int j=0;j<4;++j){
        float4 gv = *(const float4*)&gt[e0+j][k4*4];
        acc[j] += (double)xv.x*(double)gv.x + (double)xv.y*(double)gv.y
                + (double)xv.z*(double)gv.z + (double)xv.w*(double)gv.w;
      }
    }
    __syncthreads();
  }
  #pragma unroll
  for (int j=0;j<4;++j) ds[t][e0+j] = acc[j];
  __syncthreads();
  if (tid < 16){
    int tt = tid;
    int idxs[8]; double vals[8]; double sum = 0.0;
    #pragma unroll
    for (int k=0;k<8;++k){
      double best = -1e300; int bi = 0;
      for (int e=0;e<NE;++e){ double v = ds[tt][e]; if (v > best){ best = v; bi = e; } }
      ds[tt][bi] = -1e300;
      double w = 1.0 / (1.0 + exp(-best));
      idxs[k] = bi; vals[k] = w; sum += w;
    }
    double inv = 1.0 / sum;
    #pragma unroll
    for (int k=0;k<8;++k){
      topi[(size_t)(tbase+tt)*TK + k] = idxs[k];
      topw[(size_t)(tbase+tt)*TK + k] = (float)(vals[k]*inv);
    }
  }
}

// ---------------- dispatch bookkeeping ---------------------------------------
__global__ __launch_bounds__(256)
void hist_kernel(const int* __restrict__ topi, int* __restrict__ ccnt){
  __shared__ int h[NE];
  const int tid = threadIdx.x;
  if (tid < NE) h[tid] = 0;
  __syncthreads();
  atomicAdd(&h[topi[blockIdx.x*256 + tid]], 1);
  __syncthreads();
  if (tid < NE) ccnt[blockIdx.x*NE + tid] = h[tid];
}

__global__ __launch_bounds__(64)
void scan_kernel(const int* __restrict__ ccnt, int* __restrict__ cbase,
                 int* __restrict__ cntC, int* __restrict__ ebase){
  const int e = threadIdx.x;
  int run = 0;
  for (int c=0;c<NCHUNK;++c){ cbase[c*NE+e] = run; run += ccnt[c*NE+e]; }
  cntC[e] = run < CAP ? run : CAP;
  __syncthreads();
  if (e == 0){
    int s = 0;
    for (int i=0;i<NE;++i){ ebase[i] = s; s += cntC[i]; }
    ebase[NE] = s;
  }
}

__global__ __launch_bounds__(64)
void assign_kernel(const int* __restrict__ topi, const int* __restrict__ cbase,
                   int* __restrict__ pos, int* __restrict__ rowlist){
  __shared__ int es[256];
  const int tid = threadIdx.x;
  const int c = blockIdx.x;
  for (int i=tid;i<256;i+=64) es[i] = topi[c*256+i];
  __syncthreads();
  const int e = tid;
  int cntr = cbase[c*NE+e];
  for (int j=0;j<256;++j){
    if (es[j] == e){
      int n = c*256+j;
      pos[n] = cntr;
      if (cntr < CAP) rowlist[e*CAP + cntr] = n;
      ++cntr;
    }
  }
}

// ---------------- merged gate/up GEMM + fused SwiGLU (R10 core) --------------
// Blocks [0,4096): routed (R10 mapping, XCD-local). Blocks [4096,4352): shared
// expert (identity rows -> interm_s). Core: 128 rows x 64 i-cols, 4 waves 2x2;
// A bf16 gld16 (16KB), B fp32 gld16 (32KB), 16-slot XOR both; 2-barrier loop.
__global__ __launch_bounds__(256,2)
void gateup_kernel(const ushort* __restrict__ Xbf,
                   const float* __restrict__ WG, const float* __restrict__ WU,
                   const float* __restrict__ SWG, const float* __restrict__ SWU,
                   const int* __restrict__ rowlist, const int* __restrict__ cntC,
                   const int* __restrict__ ebase,
                   ushort* __restrict__ interm_r, ushort* __restrict__ interm_s)
{
  int nt, mt, cnt, outbase;
  const float *wg, *wu;
  ushort* interm;
  const bool shared_p = (blockIdx.x >= 4096u);
  const int e_rl = shared_p ? 0 : ((((blockIdx.x >> 3) >> 6) << 3) | (blockIdx.x & 7));
  if (shared_p){
    int b = blockIdx.x - 4096;
    nt = b & 7; mt = b >> 3; cnt = TOK; outbase = mt*128;
    wg = SWG + (size_t)nt*64*HD; wu = SWU + (size_t)nt*64*HD;
    interm = interm_s;
  } else {
    int rem = blockIdx.x >> 3;
    nt = rem & 7; mt = (rem >> 3) & 7;
    cnt = cntC[e_rl];
    if (mt*128 >= cnt) return;
    outbase = ebase[e_rl] + mt*128;
    const size_t wof = (size_t)e_rl*ID*HD;
    wg = WG + wof + (size_t)nt*64*HD; wu = WU + wof + (size_t)nt*64*HD;
    interm = interm_r;
  }

  __shared__ ushort aL[64*128];   // 16KB: 64 lines (=128 rows) x 16 granules
  __shared__ float  bF[128*64];   // 32KB fp32
  __shared__ int tokb[128];

  const int tid = threadIdx.x;
  if (tid < 128){
    int tokv;
    if (shared_p) tokv = mt*128 + tid;
    else tokv = (mt*128 + tid < cnt) ? (rowlist[e_rl*CAP + mt*128 + tid] >> 3) : 0;
    tokb[tid] = tokv;
  }
  __syncthreads();

  const int w = tid >> 6, l = tid & 63;
  const int wm = w >> 1, wn = w & 1;
  const int fr = l & 15, fko = (l >> 4) * 8;

  const ushort* aSrc[4];
  #pragma unroll
  for (int j=0;j<4;++j){
    int f = j*256 + tid;
    int L = f >> 4, s = f & 15;
    int g = s ^ (L & 15);
    int row = 2*L + (g >> 3);
    aSrc[j] = Xbf + (size_t)tokb[row]*HD + (g & 7)*8;
  }
  const float* bSrc[8];
  #pragma unroll
  for (int j=0;j<8;++j){
    int f = j*256 + tid;
    int R = f >> 4, s = f & 15;
    int g = s ^ (R & 15);
    const float* base = (j < 4) ? wg : wu;
    int r2 = (j < 4) ? R : (R - 64);
    bSrc[j] = base + (size_t)r2*HD + g*4;
  }

  f32x4 accg[4][2], accu[4][2];
  #pragma unroll
  for (int i=0;i<4;++i)
    #pragma unroll
    for (int j=0;j<2;++j){ accg[i][j] = (f32x4)0.0f; accu[i][j] = (f32x4)0.0f; }

  auto stage = [&](int kc){
    #pragma unroll
    for (int j=0;j<4;++j) gld16(aL + (size_t)(j*256 + w*64)*8, aSrc[j] + kc);
    #pragma unroll
    for (int j=0;j<8;++j) gld16(bF + (size_t)(j*256 + w*64)*4, bSrc[j] + kc);
  };

  stage(0);
  for (int kc=0; kc<HD; kc+=64){
    __syncthreads();   // drains vmcnt: staged tile visible
    #pragma unroll
    for (int ks=0; ks<2; ++ks){
      s16x8 a[4];
      #pragma unroll
      for (int mb=0; mb<4; ++mb){
        int r = wm*64 + mb*16 + fr;
        int agl = ks*4 + (fko >> 3);
        int g = ((r & 1) << 3) | agl;
        int L = r >> 1;
        int gs = g ^ (L & 15);
        a[mb] = *(const s16x8*)&aL[L*128 + gs*8];
      }
      #pragma unroll
      for (int cg=0; cg<2; ++cg){
        int Rg = wn*32 + cg*16 + fr;
        int gl0 = ks*8 + (fko >> 2);
        int x0 = Rg*64 + ((gl0 ^ (Rg & 15)) * 4);
        int x1 = Rg*64 + (((gl0+1) ^ (Rg & 15)) * 4);
        s16x8 bg = pack8(*(const f32x4*)&bF[x0], *(const f32x4*)&bF[x1]);
        int Ru = 64 + wn*32 + cg*16 + fr;
        int y0 = Ru*64 + ((gl0 ^ (Ru & 15)) * 4);
        int y1 = Ru*64 + (((gl0+1) ^ (Ru & 15)) * 4);
        s16x8 bu = pack8(*(const f32x4*)&bF[y0], *(const f32x4*)&bF[y1]);
        #pragma unroll
        for (int mb=0; mb<4; ++mb){
          accg[mb][cg] = __builtin_amdgcn_mfma_f32_16x16x32_bf16(a[mb], bg, accg[mb][cg], 0, 0, 0);
          accu[mb][cg] = __builtin_amdgcn_mfma_f32_16x16x32_bf16(a[mb], bu, accu[mb][cg], 0, 0, 0);
        }
      }
    }
    __syncthreads();
    if (kc + 64 < HD) stage(kc + 64);
  }

  const int rq = (l >> 4) * 4;
  #pragma unroll
  for (int mb=0; mb<4; ++mb){
    #pragma unroll
    for (int q=0; q<4; ++q){
      int rloc = wm*64 + mb*16 + rq + q;
      if (mt*128 + rloc >= cnt) continue;
      size_t orow = (size_t)(outbase + rloc);
      #pragma unroll
      for (int cg=0; cg<2; ++cg){
        float g = accg[mb][cg][q], u = accu[mb][cg][q];
        float sv = g / (1.0f + __expf(-g)) * u;   // silu(g)*u
        interm[orow*ID + (size_t)(nt*64 + wn*32 + cg*16 + fr)] = f2bf(sv);
      }
    }
  }
}

// ---------------- merged down GEMM (R10 core) --------------------------------
// Blocks [0,4096): routed -> out_rows bf16. Blocks [4096,4352): shared -> OUT.
__global__ __launch_bounds__(256,2)
void down_kernel(const ushort* __restrict__ interm_r, const ushort* __restrict__ interm_s,
                 const float* __restrict__ WD, const float* __restrict__ SWD,
                 const int* __restrict__ cntC, const int* __restrict__ ebase,
                 ushort* __restrict__ out_rows, float* __restrict__ outf)
{
  int nt, mt, cnt, abase;
  const ushort* A;
  const float* wd;
  const bool shared_p = (blockIdx.x >= 4096u);
  if (shared_p){
    int b = blockIdx.x - 4096;
    nt = b & 7; mt = b >> 3; cnt = TOK; abase = mt*128;
    A = interm_s + (size_t)abase*ID;
    wd = SWD + (size_t)nt*128*ID;
  } else {
    int x = blockIdx.x & 7; int rem = blockIdx.x >> 3;
    nt = rem & 7; mt = (rem >> 3) & 7; int e = ((rem >> 6) << 3) | x;
    cnt = cntC[e];
    if (mt*128 >= cnt) return;
    abase = ebase[e] + mt*128;
    A = interm_r + (size_t)abase*ID;
    wd = WD + (size_t)e*HD*ID + (size_t)nt*128*ID;
  }

  __shared__ ushort aL[64*128];   // 16KB
  __shared__ float  bF[128*64];   // 32KB

  const int tid = threadIdx.x;
  const int w = tid >> 6, l = tid & 63;
  const int wm = w >> 1, wn = w & 1;
  const int fr = l & 15, fko = (l >> 4) * 8;

  const ushort* aSrc[4];
  #pragma unroll
  for (int j=0;j<4;++j){
    int f = j*256 + tid;
    int L = f >> 4, s = f & 15;
    int g = s ^ (L & 15);
    int row = 2*L + (g >> 3);
    aSrc[j] = A + (size_t)row*ID + (g & 7)*8;
  }
  const float* bSrc[8];
  #pragma unroll
  for (int j=0;j<8;++j){
    int f = j*256 + tid;
    int R = f >> 4, s = f & 15;
    int g = s ^ (R & 15);
    bSrc[j] = wd + (size_t)R*ID + g*4;
  }

  f32x4 acc[4][4];
  #pragma unroll
  for (int i=0;i<4;++i)
    #pragma unroll
    for (int j=0;j<4;++j) acc[i][j] = (f32x4)0.0f;

  auto stage = [&](int kc){
    #pragma unroll
    for (int j=0;j<4;++j) gld16(aL + (size_t)(j*256 + w*64)*8, aSrc[j] + kc);
    #pragma unroll
    for (int j=0;j<8;++j) gld16(bF + (size_t)(j*256 + w*64)*4, bSrc[j] + kc);
  };

  stage(0);
  for (int kc=0; kc<ID; kc+=64){
    __syncthreads();
    #pragma unroll
    for (int ks=0; ks<2; ++ks){
      s16x8 a[4];
      #pragma unroll
      for (int mb=0; mb<4; ++mb){
        int r = wm*64 + mb*16 + fr;
        int agl = ks*4 + (fko >> 3);
        int g = ((r & 1) << 3) | agl;
        int L = r >> 1;
        int gs = g ^ (L & 15);
        a[mb] = *(const s16x8*)&aL[L*128 + gs*8];
      }
      #pragma unroll
      for (int cg=0; cg<4; ++cg){
        int R = wn*64 + cg*16 + fr;
        int gl0 = ks*8 + (fko >> 2);
        int x0 = R*64 + ((gl0 ^ (R & 15)) * 4);
        int x1 = R*64 + (((gl0+1) ^ (R & 15)) * 4);
        s16x8 bd = pack8(*(const f32x4*)&bF[x0], *(const f32x4*)&bF[x1]);
        #pragma unroll
        for (int mb=0; mb<4; ++mb){
          acc[mb][cg] = __builtin_amdgcn_mfma_f32_16x16x32_bf16(a[mb], bd, acc[mb][cg], 0, 0, 0);
        }
      }
    }
    __syncthreads();
    if (kc + 64 < ID) stage(kc + 64);
  }

  const int rq = (l >> 4) * 4;
  #pragma unroll
  for (int mb=0; mb<4; ++mb){
    #pragma unroll
    for (int q=0; q<4; ++q){
      int rloc = wm*64 + mb*16 + rq + q;
      if (mt*128 + rloc >= cnt) continue;
      #pragma unroll
      for (int cg=0; cg<4; ++cg){
        float v = acc[mb][cg][q];
        int colg = nt*128 + wn*64 + cg*16 + fr;
        if (shared_p) outf[(size_t)(mt*128 + rloc)*HD + colg] = v;
        else          out_rows[(size_t)(abase + rloc)*HD + colg] = f2bf(v);
      }
    }
  }
}

// ---------------- combine: out += sum_k topw * routed_row --------------------
__global__ __launch_bounds__(256)
void combine_kernel(const int* __restrict__ topi, const float* __restrict__ topw,
                    const int* __restrict__ pos, const int* __restrict__ ebase,
                    const ushort* __restrict__ out_rows, float* __restrict__ out)
{
  const int t = blockIdx.x;
  const int tid = threadIdx.x;
  __shared__ int rws[TK];
  __shared__ float wts[TK];
  if (tid < TK){
    int e = topi[(size_t)t*TK + tid];
    int p = pos[(size_t)t*TK + tid];
    rws[tid] = (p < CAP) ? (ebase[e] + p) : -1;
    wts[tid] = topw[(size_t)t*TK + tid];
  }
  __syncthreads();
  const int h0 = tid * 4;
  float4 acc = *(float4*)(out + (size_t)t*HD + h0);
  #pragma unroll
  for (int k=0;k<TK;++k){
    int r = rws[k];
    if (r < 0) continue;
    ushort4 v = *(const ushort4*)(out_rows + (size_t)r*HD + h0);
    float wk = wts[k];
    acc.x += wk*bf2f(v.x); acc.y += wk*bf2f(v.y);
    acc.z += wk*bf2f(v.z); acc.w += wk*bf2f(v.w);
  }
  *(float4*)(out + (size_t)t*HD + h0) = acc;
}

// ---------------- launch ------------------------------------------------------
extern "C" void kernel_launch(void* const* d_in, const int* in_sizes, int n_in,
                              void* d_out, int out_size, void* d_ws, size_t ws_size,
                              hipStream_t stream)
{
  (void)in_sizes; (void)n_in; (void)out_size; (void)ws_size;
  const float* X   = (const float*)d_in[0];
  const float* GW  = (const float*)d_in[1];
  const float* SWG = (const float*)d_in[2];
  const float* SWU = (const float*)d_in[3];
  const float* SWD = (const float*)d_in[4];
  const float* EWG = (const float*)d_in[5];
  const float* EWU = (const float*)d_in[6];
  const float* EWD = (const float*)d_in[7];
  float* OUT = (float*)d_out;

  char* p = (char*)d_ws;
  int*    topi    = (int*)p;      p += (size_t)NROUTE*4;
  float*  topw    = (float*)p;    p += (size_t)NROUTE*4;
  int*    pos     = (int*)p;      p += (size_t)NROUTE*4;
  int*    ccnt    = (int*)p;      p += (size_t)NCHUNK*NE*4;
  int*    cbase   = (int*)p;      p += (size_t)NCHUNK*NE*4;
  int*    cntC    = (int*)p;      p += 256;
  int*    ebase   = (int*)p;      p += 512;
  int*    rowlist = (int*)p;      p += (size_t)NE*CAP*4;
  ushort* Xbf     = (ushort*)p;   p += (size_t)TOK*HD*2;
  ushort* interm_r= (ushort*)p;   p += (size_t)(NROUTE+128)*ID*2;
  ushort* interm_s= (ushort*)p;   p += (size_t)TOK*ID*2;
  ushort* out_rows= (ushort*)p;   p += (size_t)NROUTE*HD*2;

  gating_kernel<<<256, 256, 0, stream>>>(X, GW, Xbf, topi, topw);
  hist_kernel<<<NCHUNK, 256, 0, stream>>>(topi, ccnt);
  scan_kernel<<<1, 64, 0, stream>>>(ccnt, cbase, cntC, ebase);
  assign_kernel<<<NCHUNK, 64, 0, stream>>>(topi, cbase, pos, rowlist);

  gateup_kernel<<<4352, 256, 0, stream>>>(Xbf, EWG, EWU, SWG, SWU,
                                          rowlist, cntC, ebase, interm_r, interm_s);
  down_kernel<<<4352, 256, 0, stream>>>(interm_r, interm_s, EWD, SWD,
                                        cntC, ebase, out_rows, OUT);

  combine_kernel<<<TOK, 256, 0, stream>>>(topi, topw, pos, ebase, out_rows, OUT);
}